// Round 19
// baseline (140.329 us; speedup 1.0000x reference)
//
#include <hip/hip_runtime.h>
#include <hip/hip_bf16.h>
#include <math.h>

typedef unsigned short u16;
typedef __attribute__((ext_vector_type(8))) short short8;
typedef __attribute__((ext_vector_type(4))) float f32x4;
typedef __attribute__((ext_vector_type(4))) unsigned short u16x4;
typedef __attribute__((ext_vector_type(4))) unsigned int u32x4;

#define DEVI static __device__ __forceinline__

DEVI u16 f2bf(float f){
  union { float f; unsigned u; } c; c.f = f;
  unsigned r = (c.u + 0x7fffu + ((c.u >> 16) & 1u)) >> 16;
  return (u16)r;
}

DEVI unsigned cvtpk(float lo, float hi){
  unsigned r;
  asm("v_cvt_pk_bf16_f32 %0, %1, %2" : "=v"(r) : "v"(lo), "v"(hi));
  return r;
}

DEVI void async16(const void* g, void* l){
  __builtin_amdgcn_global_load_lds(
    (const __attribute__((address_space(1))) unsigned int*)g,
    (__attribute__((address_space(3))) unsigned int*)l, 16, 0, 0);
}

// counted-vmcnt barrier: wait until <=N VMEM instr outstanding, then barrier.
#define WAIT_BAR(N) asm volatile("s_waitcnt vmcnt(" #N ") lgkmcnt(0)\n\ts_barrier" ::: "memory")

// GEMM staging tiles (4 slots/row of 16B): physical chunk for (row r, group g)
#define ACHUNK(r, g) (((r) << 2) | (((g) + ((r) >> 1)) & 3))
// attn 64-row tiles (8 slots/row), FULL-r rotation: conflict-free ds_read_b128.
#define KCH(r, g) (((r) << 3) | (((g) + (r)) & 7))

// ---------------- fused fp32 -> bf16 conversion (x, Wqkv, Wproj) ----------------
__global__ __launch_bounds__(256) void cvt3(const float4* __restrict__ x,
                                            const float4* __restrict__ wq,
                                            const float4* __restrict__ wp,
                                            u16* __restrict__ xb,
                                            u16* __restrict__ wqb,
                                            u16* __restrict__ wpb){
  int i = blockIdx.x * 256 + threadIdx.x;
  const float4* s; u16* d; int off;
  if (i < 1048576)      { s = x;  d = xb;  off = i; }
  else if (i < 2621440) { s = wq; d = wqb; off = i - 1048576; }
  else                  { s = wp; d = wpb; off = i - 2621440; }
  float4 v = s[off];
  u16x4 o;
  o.x = f2bf(v.x); o.y = f2bf(v.y); o.z = f2bf(v.z); o.w = f2bf(v.w);
  *(u16x4*)(d + (size_t)off * 4) = o;
}

// ---------------- qkv GEMM (128x128, 4 waves, paired tiles, stage interval) ------
// Epilogue: q pre-scaled by log2(e) so attn softmax can use raw exp2.
__global__ __launch_bounds__(256) void gemm_qkv(const u16* __restrict__ A,
                                                const u16* __restrict__ B,
                                                const float* __restrict__ qg,
                                                const float* __restrict__ at_,
                                                u16* __restrict__ qb,
                                                u16* __restrict__ kb,
                                                u16* __restrict__ vT){
  const int K = 2048;
  __shared__ __align__(16) u16 As[4][4096];
  __shared__ __align__(16) u16 Bs[4][4096];
  const int bid = blockIdx.x;
  const int xcd = bid & 7, pos = bid >> 3;          // pos in [0,48)
  const int xm = xcd & 1, xn = xcd >> 1;            // XCD grid 2(m) x 4(n)
  const int mIdx = xm * 8 + (pos & 7);
  const int nIdx = xn * 6 + (pos >> 3);
  const int tid  = threadIdx.x;
  const int lane = tid & 63, wid = tid >> 6;
  const int wr = wid >> 1, wc = wid & 1;
  const int fr = lane & 15, fg = lane >> 4;
  const int mBase = mIdx * 128, nBase = nIdx * 128;

  f32x4 acc[4][4];
  for (int m = 0; m < 4; ++m)
    for (int n = 0; n < 4; ++n)
      for (int e = 0; e < 4; ++e) acc[m][n][e] = 0.f;

  const int c0 = tid, c1 = tid + 256;
  const int p0 = c0 >> 2, q0 = ((c0 & 3) - (p0 >> 1)) & 3;
  const int p1 = c1 >> 2, q1 = ((c1 & 3) - (p1 >> 1)) & 3;
  const u16* Ab = A + (size_t)mBase * K;
  const u16* Bb = B + (size_t)nBase * K;

  int ca[4], cb[4];
#pragma unroll
  for (int m = 0; m < 4; ++m){ const int r = wr * 64 + m * 16 + fr; ca[m] = ACHUNK(r, fg); }
#pragma unroll
  for (int n = 0; n < 4; ++n){ const int r = wc * 64 + n * 16 + fr; cb[n] = ACHUNK(r, fg); }

#define STAGE_QKV(kt) do {                                                 \
    const int b_ = (kt) & 3;                                               \
    const int kO_ = (kt) * 32;                                             \
    async16(Ab + (size_t)p0 * K + kO_ + q0 * 8, As[b_] + c0 * 8);          \
    async16(Ab + (size_t)p1 * K + kO_ + q1 * 8, As[b_] + c1 * 8);          \
    async16(Bb + (size_t)p0 * K + kO_ + q0 * 8, Bs[b_] + c0 * 8);          \
    async16(Bb + (size_t)p1 * K + kO_ + q1 * 8, Bs[b_] + c1 * 8);          \
  } while (0)

  STAGE_QKV(0); STAGE_QKV(1); STAGE_QKV(2); STAGE_QKV(3);

#pragma unroll 1
  for (int p = 0; p < 32; ++p){
    if (p < 31) WAIT_BAR(8);
    else        WAIT_BAR(0);
#pragma unroll
    for (int kk = 0; kk < 2; ++kk){
      const int cur = (2 * p + kk) & 3;
      short8 a[4], b[4];
#pragma unroll
      for (int m = 0; m < 4; ++m)
        a[m] = *(const short8*)(As[cur] + ca[m] * 8);
#pragma unroll
      for (int n = 0; n < 4; ++n)
        b[n] = *(const short8*)(Bs[cur] + cb[n] * 8);
      __builtin_amdgcn_s_setprio(1);
#pragma unroll
      for (int m = 0; m < 4; ++m)
#pragma unroll
        for (int n = 0; n < 4; ++n)
          acc[m][n] = __builtin_amdgcn_mfma_f32_16x16x32_bf16(a[m], b[n], acc[m][n], 0, 0, 0);
      __builtin_amdgcn_s_setprio(0);
    }
    __builtin_amdgcn_s_barrier();
    if (p < 30){ STAGE_QKV(2 * p + 4); STAGE_QKV(2 * p + 5); }
  }
#undef STAGE_QKV

  // fused epilogue. col64-block: 0..31 = q heads, 32..39 = k heads, 40..47 = v heads
  const int nb64 = nIdx * 2 + wc;
  if (nb64 < 40){
    const bool isq = nb64 < 32;
    const int h = isq ? nb64 : (nb64 - 32);
    // q additionally scaled by log2(e) so softmax uses exp2 directly
    const float gsc = isq ? (qg[h] * at_[h] * 0.125f * 1.44269504f) : 1.0f;
    u16* dst = isq ? qb : kb;
#pragma unroll
    for (int m = 0; m < 4; ++m)
#pragma unroll
      for (int e = 0; e < 4; ++e){
        const int t = mBase + wr * 64 + m * 16 + fg * 4 + e;
        const float ft = (float)t;
#pragma unroll
        for (int np = 0; np < 2; ++np){
          const int d = np * 16 + fr;
          const float ang = ft * ((float)d * 0.03125f);
          float sn, cs; sincosf(ang, &sn, &cs);
          const float x1 = acc[m][np][e], x2 = acc[m][np + 2][e];
          u16* base = dst + ((size_t)h * 2048 + t) * 64 + d;
          base[0]  = f2bf((x1 * cs - x2 * sn) * gsc);
          base[32] = f2bf((x1 * sn + x2 * cs) * gsc);
        }
      }
  } else {
    const int h = nb64 - 40;
#pragma unroll
    for (int m = 0; m < 4; ++m){
      const int t0 = mBase + wr * 64 + m * 16 + fg * 4;
#pragma unroll
      for (int n = 0; n < 4; ++n){
        const int d = n * 16 + fr;
        u16x4 pk;
#pragma unroll
        for (int e = 0; e < 4; ++e) pk[e] = f2bf(acc[m][n][e]);
        *(u16x4*)(vT + ((size_t)h * 64 + d) * 2048 + t0) = pk;
      }
    }
  }
}

// ---------------- causal flash attention v7+exp2 --------------------------------
// R17 structure (4-deep K/V, KVBLK=64, counted vmcnt, KCH conflict-free) with
// base-2 softmax (q pre-scaled by log2e; THR = 8*log2e).
__global__ __launch_bounds__(256) void attn_fwd(const u16* __restrict__ qb,
                                                const u16* __restrict__ kb,
                                                const u16* __restrict__ vT,
                                                u16* __restrict__ yb){
  const int bx = blockIdx.x, h = blockIdx.y;
  const int hk = h >> 2;
  const int tid = threadIdx.x;
  const int lane = tid & 63, wid = tid >> 6;
  const int fr = lane & 15, fg = lane >> 4;

  __shared__ __align__(16) u16 Ks[4][4096];   // chunk KCH(rho,g) : K[pi(rho)][g*8..+7]
  __shared__ __align__(16) u16 Vs[4][4096];   // chunk KCH(d,g)   : V^T[d][g*8..+7]

  const u16* kbh = kb + (size_t)hk * 2048 * 64;
  const u16* vTh = vT + (size_t)hk * 64 * 2048;

  const int c0 = tid, c1 = tid + 256;
  const int p0 = c0 >> 3, q0 = ((c0 & 7) - p0) & 7;
  const int p1 = c1 >> 3, q1 = ((c1 & 7) - p1) & 7;
  // pi row permute (K only): [kc cc fg1 fg0 r1 r0] -> kc*32 + fg*8 + cc*4 + r
  const int pr0 = ((p0 >> 5) << 5) | (((p0 >> 2) & 3) << 3) | (((p0 >> 4) & 1) << 2) | (p0 & 3);
  const int pr1 = ((p1 >> 5) << 5) | (((p1 >> 2) & 3) << 3) | (((p1 >> 4) & 1) << 2) | (p1 & 3);

  int ck[2][4];
#pragma unroll
  for (int kc = 0; kc < 2; ++kc)
#pragma unroll
    for (int cf = 0; cf < 4; ++cf)
      ck[kc][cf] = KCH(cf * 16 + fr, kc * 4 + fg);

#define STAGE_KV(kt) do {                                                   \
    const int b_ = (kt) & 3;                                                \
    const size_t kO_ = (size_t)(kt) * 64;                                   \
    async16(kbh + (kO_ + pr0) * 64 + q0 * 8,        Ks[b_] + (size_t)c0 * 8); \
    async16(kbh + (kO_ + pr1) * 64 + q1 * 8,        Ks[b_] + (size_t)c1 * 8); \
    async16(vTh + (size_t)p0 * 2048 + kO_ + q0 * 8, Vs[b_] + (size_t)c0 * 8); \
    async16(vTh + (size_t)p1 * 2048 + kO_ + q1 * 8, Vs[b_] + (size_t)c1 * 8); \
  } while (0)

#pragma unroll 1
  for (int seg = 0; seg < 2; ++seg){
    const int qt = seg ? (31 - bx) : bx;
    const int nt = qt + 1;
    const int qrow0 = qt * 64 + wid * 16;
    const int q = qrow0 + fr;          // this lane's q-row

    short8 qf[2];
    {
      const u16* qp = qb + ((size_t)h * 2048 + q) * 64 + fg * 8;
      qf[0] = *(const short8*)(qp);
      qf[1] = *(const short8*)(qp + 32);
    }

    float mrow = -1e30f, lrow = 0.f;
    f32x4 o[4];
    for (int df = 0; df < 4; ++df)
      for (int e = 0; e < 4; ++e) o[df][e] = 0.f;

    STAGE_KV(0);
    if (nt > 1) STAGE_KV(1);
    if (nt > 2) STAGE_KV(2);

#pragma unroll 1
    for (int kt = 0; kt < nt; ++kt){
      const int rem = nt - 1 - kt;
      if (rem >= 2)      WAIT_BAR(8);
      else if (rem == 1) WAIT_BAR(4);
      else               WAIT_BAR(0);
      const u16* Kb = Ks[kt & 3];
      const u16* Vb = Vs[kt & 3];

      // S'^T : s[cf][r] = S'[q][kt*64 + (cf>>1)*32 + fg*8 + (cf&1)*4 + r]
      f32x4 s[4];
      __builtin_amdgcn_s_setprio(1);
#pragma unroll
      for (int cf = 0; cf < 4; ++cf){
        for (int e = 0; e < 4; ++e) s[cf][e] = 0.f;
#pragma unroll
        for (int kc = 0; kc < 2; ++kc){
          short8 kf = *(const short8*)(Kb + ck[kc][cf] * 8);
          s[cf] = __builtin_amdgcn_mfma_f32_16x16x32_bf16(kf, qf[kc], s[cf], 0, 0, 0);
        }
      }
      __builtin_amdgcn_s_setprio(0);

      if (kt * 64 + 63 > qrow0){
#pragma unroll
        for (int cf = 0; cf < 4; ++cf){
          const int kb0 = kt * 64 + (cf >> 1) * 32 + (cf & 1) * 4 + fg * 8;
#pragma unroll
          for (int r = 0; r < 4; ++r)
            if (kb0 + r > q) s[cf][r] = -1e30f;
        }
      }

      // lane-local softmax (base-2 domain) with defer-max (THR = 8*log2e)
      float m0 = fmaxf(fmaxf(s[0][0], s[0][1]), fmaxf(s[0][2], s[0][3]));
      float m1 = fmaxf(fmaxf(s[1][0], s[1][1]), fmaxf(s[1][2], s[1][3]));
      float m2 = fmaxf(fmaxf(s[2][0], s[2][1]), fmaxf(s[2][2], s[2][3]));
      float m3 = fmaxf(fmaxf(s[3][0], s[3][1]), fmaxf(s[3][2], s[3][3]));
      float mt = fmaxf(fmaxf(m0, m1), fmaxf(m2, m3));
      mt = fmaxf(mt, __shfl_xor(mt, 16));
      mt = fmaxf(mt, __shfl_xor(mt, 32));
      if (!__all(mt <= mrow + 11.5416f)){
        const float mn = fmaxf(mrow, mt);
        const float al = exp2f(mrow - mn);
        lrow *= al;
#pragma unroll
        for (int df = 0; df < 4; ++df)
#pragma unroll
          for (int e = 0; e < 4; ++e) o[df][e] *= al;
        mrow = mn;
      }
      float rs = 0.f;
#pragma unroll
      for (int cf = 0; cf < 4; ++cf){
#pragma unroll
        for (int r = 0; r < 4; ++r){
          s[cf][r] = exp2f(s[cf][r] - mrow);
          rs += s[cf][r];
        }
      }
      rs += __shfl_xor(rs, 16);
      rs += __shfl_xor(rs, 32);
      lrow += rs;

      union { u32x4 u; short8 s8; } pb_0, pb_1;
      pb_0.u[0] = cvtpk(s[0][0], s[0][1]); pb_0.u[1] = cvtpk(s[0][2], s[0][3]);
      pb_0.u[2] = cvtpk(s[1][0], s[1][1]); pb_0.u[3] = cvtpk(s[1][2], s[1][3]);
      pb_1.u[0] = cvtpk(s[2][0], s[2][1]); pb_1.u[1] = cvtpk(s[2][2], s[2][3]);
      pb_1.u[2] = cvtpk(s[3][0], s[3][1]); pb_1.u[3] = cvtpk(s[3][2], s[3][3]);

      __builtin_amdgcn_s_setprio(1);
#pragma unroll
      for (int df = 0; df < 4; ++df){
        short8 v0 = *(const short8*)(Vb + ck[0][df] * 8);
        short8 v1 = *(const short8*)(Vb + ck[1][df] * 8);
        o[df] = __builtin_amdgcn_mfma_f32_16x16x32_bf16(v0, pb_0.s8, o[df], 0, 0, 0);
        o[df] = __builtin_amdgcn_mfma_f32_16x16x32_bf16(v1, pb_1.s8, o[df], 0, 0, 0);
      }
      __builtin_amdgcn_s_setprio(0);

      __builtin_amdgcn_s_barrier();
      if (kt + 3 < nt) STAGE_KV(kt + 3);
    }

    const float inv = 1.f / lrow;
#pragma unroll
    for (int df = 0; df < 4; ++df){
      u16x4 pk;
#pragma unroll
      for (int e = 0; e < 4; ++e) pk[e] = f2bf(o[df][e] * inv);
      *(u16x4*)(yb + (size_t)q * 2048 + h * 64 + df * 16 + fg * 4) = pk;
    }
  }
#undef STAGE_KV
}

// ---------------- proj GEMM (128x128, 4 waves, paired tiles, stage interval) -----
__global__ __launch_bounds__(256) void gemm_bt(const u16* __restrict__ A,
                                               const u16* __restrict__ B,
                                               float* __restrict__ C,
                                               int M, int N, int K){
  __shared__ __align__(16) u16 As[4][4096];
  __shared__ __align__(16) u16 Bs[4][4096];
  const int bid = blockIdx.x;
  const int xcd = bid & 7, pos = bid >> 3;          // pos in [0,32)
  const int xm = xcd & 1, xn = xcd >> 1;            // XCD grid 2(m) x 4(n)
  const int mIdx = xm * 8 + (pos & 7);
  const int nIdx = xn * 4 + (pos >> 3);
  const int tid  = threadIdx.x;
  const int lane = tid & 63, wid = tid >> 6;
  const int wr = wid >> 1, wc = wid & 1;
  const int fr = lane & 15, fg = lane >> 4;
  const int mBase = mIdx * 128, nBase = nIdx * 128;

  f32x4 acc[4][4];
  for (int m = 0; m < 4; ++m)
    for (int n = 0; n < 4; ++n)
      for (int e = 0; e < 4; ++e) acc[m][n][e] = 0.f;

  const int c0 = tid, c1 = tid + 256;
  const int p0 = c0 >> 2, q0 = ((c0 & 3) - (p0 >> 1)) & 3;
  const int p1 = c1 >> 2, q1 = ((c1 & 3) - (p1 >> 1)) & 3;
  const u16* Ab = A + (size_t)mBase * K;
  const u16* Bb = B + (size_t)nBase * K;

  int ca[4], cb[4];
#pragma unroll
  for (int m = 0; m < 4; ++m){ const int r = wr * 64 + m * 16 + fr; ca[m] = ACHUNK(r, fg); }
#pragma unroll
  for (int n = 0; n < 4; ++n){ const int r = wc * 64 + n * 16 + fr; cb[n] = ACHUNK(r, fg); }

#define STAGE_BT(kt) do {                                                  \
    const int b_ = (kt) & 3;                                               \
    const int kO_ = (kt) * 32;                                             \
    async16(Ab + (size_t)p0 * K + kO_ + q0 * 8, As[b_] + c0 * 8);          \
    async16(Ab + (size_t)p1 * K + kO_ + q1 * 8, As[b_] + c1 * 8);          \
    async16(Bb + (size_t)p0 * K + kO_ + q0 * 8, Bs[b_] + c0 * 8);          \
    async16(Bb + (size_t)p1 * K + kO_ + q1 * 8, Bs[b_] + c1 * 8);          \
  } while (0)

  STAGE_BT(0); STAGE_BT(1); STAGE_BT(2); STAGE_BT(3);

  const int np = K >> 6;   // pairs
#pragma unroll 1
  for (int p = 0; p < np; ++p){
    if (p < np - 1) WAIT_BAR(8);
    else            WAIT_BAR(0);
#pragma unroll
    for (int kk = 0; kk < 2; ++kk){
      const int cur = (2 * p + kk) & 3;
      short8 a[4], b[4];
#pragma unroll
      for (int m = 0; m < 4; ++m)
        a[m] = *(const short8*)(As[cur] + ca[m] * 8);
#pragma unroll
      for (int n = 0; n < 4; ++n)
        b[n] = *(const short8*)(Bs[cur] + cb[n] * 8);
      __builtin_amdgcn_s_setprio(1);
#pragma unroll
      for (int m = 0; m < 4; ++m)
#pragma unroll
        for (int n = 0; n < 4; ++n)
          acc[m][n] = __builtin_amdgcn_mfma_f32_16x16x32_bf16(a[m], b[n], acc[m][n], 0, 0, 0);
      __builtin_amdgcn_s_setprio(0);
    }
    __builtin_amdgcn_s_barrier();
    if (p < np - 2){ STAGE_BT(2 * p + 4); STAGE_BT(2 * p + 5); }
  }
#undef STAGE_BT

  for (int m = 0; m < 4; ++m){
    const int row = mBase + wr * 64 + m * 16 + fg * 4;
    for (int n = 0; n < 4; ++n){
      const int col = nBase + wc * 64 + n * 16 + fr;
      for (int e = 0; e < 4; ++e)
        C[(size_t)(row + e) * N + col] = acc[m][n][e];
    }
  }
}

extern "C" void kernel_launch(void* const* d_in, const int* in_sizes, int n_in,
                              void* d_out, int out_size, void* d_ws, size_t ws_size,
                              hipStream_t stream){
  (void)in_sizes; (void)n_in; (void)out_size; (void)ws_size;
  const float* x     = (const float*)d_in[0];
  const float* Wqkv  = (const float*)d_in[1];
  const float* Wproj = (const float*)d_in[2];
  const float* qg    = (const float*)d_in[3];
  const float* at    = (const float*)d_in[4];
  float* out = (float*)d_out;

  u16* xb     = (u16*)d_ws;              // 2048*2048
  u16* wqkvb  = xb + 4194304;            // 3072*2048
  u16* wprojb = wqkvb + 6291456;         // 2048*2048
  u16* qbuf   = wprojb + 4194304;        // 32*2048*64
  u16* kbuf   = qbuf + 4194304;          // 8*2048*64
  u16* vTb    = kbuf + 1048576;          // 8*64*2048
  u16* ybuf   = vTb + 1048576;           // 2048*2048

  cvt3<<<14336, 256, 0, stream>>>((const float4*)x, (const float4*)Wqkv,
                                  (const float4*)Wproj, xb, wqkvb, wprojb);
  gemm_qkv<<<384, 256, 0, stream>>>(xb, wqkvb, qg, at, qbuf, kbuf, vTb);
  attn_fwd<<<dim3(16, 32), 256, 0, stream>>>(qbuf, kbuf, vTb, ybuf);
  gemm_bt<<<256, 256, 0, stream>>>(ybuf, wprojb, out, 2048, 2048, 2048);
}

// Round 20
// 133.201 us; speedup vs baseline: 1.0535x; 1.0535x over previous
//
#include <hip/hip_runtime.h>
#include <hip/hip_bf16.h>
#include <math.h>

typedef unsigned short u16;
typedef __attribute__((ext_vector_type(8))) short short8;
typedef __attribute__((ext_vector_type(4))) float f32x4;
typedef __attribute__((ext_vector_type(4))) unsigned short u16x4;
typedef __attribute__((ext_vector_type(4))) unsigned int u32x4;

#define DEVI static __device__ __forceinline__

DEVI u16 f2bf(float f){
  union { float f; unsigned u; } c; c.f = f;
  unsigned r = (c.u + 0x7fffu + ((c.u >> 16) & 1u)) >> 16;
  return (u16)r;
}

DEVI unsigned cvtpk(float lo, float hi){
  unsigned r;
  asm("v_cvt_pk_bf16_f32 %0, %1, %2" : "=v"(r) : "v"(lo), "v"(hi));
  return r;
}

// raw hardware 2^x (v_exp_f32), no libm range handling — fine for bf16 P-values
DEVI float ex2(float x){
  float r;
  asm("v_exp_f32 %0, %1" : "=v"(r) : "v"(x));
  return r;
}

DEVI void async16(const void* g, void* l){
  __builtin_amdgcn_global_load_lds(
    (const __attribute__((address_space(1))) unsigned int*)g,
    (__attribute__((address_space(3))) unsigned int*)l, 16, 0, 0);
}

// counted-vmcnt barrier: wait until <=N VMEM instr outstanding, then barrier.
#define WAIT_BAR(N) asm volatile("s_waitcnt vmcnt(" #N ") lgkmcnt(0)\n\ts_barrier" ::: "memory")

// GEMM staging tiles (4 slots/row of 16B): physical chunk for (row r, group g)
#define ACHUNK(r, g) (((r) << 2) | (((g) + ((r) >> 1)) & 3))
// attn 64-row tiles (8 slots/row), FULL-r rotation: conflict-free ds_read_b128.
#define KCH(r, g) (((r) << 3) | (((g) + (r)) & 7))

// ---------------- fused fp32 -> bf16 conversion (x, Wqkv, Wproj) ----------------
__global__ __launch_bounds__(256) void cvt3(const float4* __restrict__ x,
                                            const float4* __restrict__ wq,
                                            const float4* __restrict__ wp,
                                            u16* __restrict__ xb,
                                            u16* __restrict__ wqb,
                                            u16* __restrict__ wpb){
  int i = blockIdx.x * 256 + threadIdx.x;
  const float4* s; u16* d; int off;
  if (i < 1048576)      { s = x;  d = xb;  off = i; }
  else if (i < 2621440) { s = wq; d = wqb; off = i - 1048576; }
  else                  { s = wp; d = wpb; off = i - 2621440; }
  float4 v = s[off];
  u16x4 o;
  o.x = f2bf(v.x); o.y = f2bf(v.y); o.z = f2bf(v.z); o.w = f2bf(v.w);
  *(u16x4*)(d + (size_t)off * 4) = o;
}

// ---------------- qkv GEMM (128x128, 4 waves, paired tiles, stage interval) ------
// Epilogue: q pre-scaled by log2(e) so attn softmax can use raw v_exp_f32.
__global__ __launch_bounds__(256) void gemm_qkv(const u16* __restrict__ A,
                                                const u16* __restrict__ B,
                                                const float* __restrict__ qg,
                                                const float* __restrict__ at_,
                                                u16* __restrict__ qb,
                                                u16* __restrict__ kb,
                                                u16* __restrict__ vT){
  const int K = 2048;
  __shared__ __align__(16) u16 As[4][4096];
  __shared__ __align__(16) u16 Bs[4][4096];
  const int bid = blockIdx.x;
  const int xcd = bid & 7, pos = bid >> 3;          // pos in [0,48)
  const int xm = xcd & 1, xn = xcd >> 1;            // XCD grid 2(m) x 4(n)
  const int mIdx = xm * 8 + (pos & 7);
  const int nIdx = xn * 6 + (pos >> 3);
  const int tid  = threadIdx.x;
  const int lane = tid & 63, wid = tid >> 6;
  const int wr = wid >> 1, wc = wid & 1;
  const int fr = lane & 15, fg = lane >> 4;
  const int mBase = mIdx * 128, nBase = nIdx * 128;

  f32x4 acc[4][4];
  for (int m = 0; m < 4; ++m)
    for (int n = 0; n < 4; ++n)
      for (int e = 0; e < 4; ++e) acc[m][n][e] = 0.f;

  const int c0 = tid, c1 = tid + 256;
  const int p0 = c0 >> 2, q0 = ((c0 & 3) - (p0 >> 1)) & 3;
  const int p1 = c1 >> 2, q1 = ((c1 & 3) - (p1 >> 1)) & 3;
  const u16* Ab = A + (size_t)mBase * K;
  const u16* Bb = B + (size_t)nBase * K;

  int ca[4], cb[4];
#pragma unroll
  for (int m = 0; m < 4; ++m){ const int r = wr * 64 + m * 16 + fr; ca[m] = ACHUNK(r, fg); }
#pragma unroll
  for (int n = 0; n < 4; ++n){ const int r = wc * 64 + n * 16 + fr; cb[n] = ACHUNK(r, fg); }

#define STAGE_QKV(kt) do {                                                 \
    const int b_ = (kt) & 3;                                               \
    const int kO_ = (kt) * 32;                                             \
    async16(Ab + (size_t)p0 * K + kO_ + q0 * 8, As[b_] + c0 * 8);          \
    async16(Ab + (size_t)p1 * K + kO_ + q1 * 8, As[b_] + c1 * 8);          \
    async16(Bb + (size_t)p0 * K + kO_ + q0 * 8, Bs[b_] + c0 * 8);          \
    async16(Bb + (size_t)p1 * K + kO_ + q1 * 8, Bs[b_] + c1 * 8);          \
  } while (0)

  STAGE_QKV(0); STAGE_QKV(1); STAGE_QKV(2); STAGE_QKV(3);

#pragma unroll 1
  for (int p = 0; p < 32; ++p){
    if (p < 31) WAIT_BAR(8);
    else        WAIT_BAR(0);
#pragma unroll
    for (int kk = 0; kk < 2; ++kk){
      const int cur = (2 * p + kk) & 3;
      short8 a[4], b[4];
#pragma unroll
      for (int m = 0; m < 4; ++m)
        a[m] = *(const short8*)(As[cur] + ca[m] * 8);
#pragma unroll
      for (int n = 0; n < 4; ++n)
        b[n] = *(const short8*)(Bs[cur] + cb[n] * 8);
      __builtin_amdgcn_s_setprio(1);
#pragma unroll
      for (int m = 0; m < 4; ++m)
#pragma unroll
        for (int n = 0; n < 4; ++n)
          acc[m][n] = __builtin_amdgcn_mfma_f32_16x16x32_bf16(a[m], b[n], acc[m][n], 0, 0, 0);
      __builtin_amdgcn_s_setprio(0);
    }
    __builtin_amdgcn_s_barrier();
    if (p < 30){ STAGE_QKV(2 * p + 4); STAGE_QKV(2 * p + 5); }
  }
#undef STAGE_QKV

  // fused epilogue. col64-block: 0..31 = q heads, 32..39 = k heads, 40..47 = v heads
  const int nb64 = nIdx * 2 + wc;
  if (nb64 < 40){
    const bool isq = nb64 < 32;
    const int h = isq ? nb64 : (nb64 - 32);
    // q additionally scaled by log2(e) so softmax uses 2^x directly
    const float gsc = isq ? (qg[h] * at_[h] * 0.125f * 1.44269504f) : 1.0f;
    u16* dst = isq ? qb : kb;
#pragma unroll
    for (int m = 0; m < 4; ++m)
#pragma unroll
      for (int e = 0; e < 4; ++e){
        const int t = mBase + wr * 64 + m * 16 + fg * 4 + e;
        const float ft = (float)t;
#pragma unroll
        for (int np = 0; np < 2; ++np){
          const int d = np * 16 + fr;
          const float ang = ft * ((float)d * 0.03125f);
          float sn, cs; sincosf(ang, &sn, &cs);
          const float x1 = acc[m][np][e], x2 = acc[m][np + 2][e];
          u16* base = dst + ((size_t)h * 2048 + t) * 64 + d;
          base[0]  = f2bf((x1 * cs - x2 * sn) * gsc);
          base[32] = f2bf((x1 * sn + x2 * cs) * gsc);
        }
      }
  } else {
    const int h = nb64 - 40;
#pragma unroll
    for (int m = 0; m < 4; ++m){
      const int t0 = mBase + wr * 64 + m * 16 + fg * 4;
#pragma unroll
      for (int n = 0; n < 4; ++n){
        const int d = n * 16 + fr;
        u16x4 pk;
#pragma unroll
        for (int e = 0; e < 4; ++e) pk[e] = f2bf(acc[m][n][e]);
        *(u16x4*)(vT + ((size_t)h * 64 + d) * 2048 + t0) = pk;
      }
    }
  }
}

// ---------------- causal flash attention v7+raw-exp2 -----------------------------
// R17 structure (4-deep K/V, KVBLK=64, counted vmcnt, KCH conflict-free) with
// base-2 softmax via raw v_exp_f32 (q pre-scaled by log2e; THR = 8*log2e).
__global__ __launch_bounds__(256) void attn_fwd(const u16* __restrict__ qb,
                                                const u16* __restrict__ kb,
                                                const u16* __restrict__ vT,
                                                u16* __restrict__ yb){
  const int bx = blockIdx.x, h = blockIdx.y;
  const int hk = h >> 2;
  const int tid = threadIdx.x;
  const int lane = tid & 63, wid = tid >> 6;
  const int fr = lane & 15, fg = lane >> 4;

  __shared__ __align__(16) u16 Ks[4][4096];   // chunk KCH(rho,g) : K[pi(rho)][g*8..+7]
  __shared__ __align__(16) u16 Vs[4][4096];   // chunk KCH(d,g)   : V^T[d][g*8..+7]

  const u16* kbh = kb + (size_t)hk * 2048 * 64;
  const u16* vTh = vT + (size_t)hk * 64 * 2048;

  const int c0 = tid, c1 = tid + 256;
  const int p0 = c0 >> 3, q0 = ((c0 & 7) - p0) & 7;
  const int p1 = c1 >> 3, q1 = ((c1 & 7) - p1) & 7;
  // pi row permute (K only): [kc cc fg1 fg0 r1 r0] -> kc*32 + fg*8 + cc*4 + r
  const int pr0 = ((p0 >> 5) << 5) | (((p0 >> 2) & 3) << 3) | (((p0 >> 4) & 1) << 2) | (p0 & 3);
  const int pr1 = ((p1 >> 5) << 5) | (((p1 >> 2) & 3) << 3) | (((p1 >> 4) & 1) << 2) | (p1 & 3);

  int ck[2][4];
#pragma unroll
  for (int kc = 0; kc < 2; ++kc)
#pragma unroll
    for (int cf = 0; cf < 4; ++cf)
      ck[kc][cf] = KCH(cf * 16 + fr, kc * 4 + fg);

#define STAGE_KV(kt) do {                                                   \
    const int b_ = (kt) & 3;                                                \
    const size_t kO_ = (size_t)(kt) * 64;                                   \
    async16(kbh + (kO_ + pr0) * 64 + q0 * 8,        Ks[b_] + (size_t)c0 * 8); \
    async16(kbh + (kO_ + pr1) * 64 + q1 * 8,        Ks[b_] + (size_t)c1 * 8); \
    async16(vTh + (size_t)p0 * 2048 + kO_ + q0 * 8, Vs[b_] + (size_t)c0 * 8); \
    async16(vTh + (size_t)p1 * 2048 + kO_ + q1 * 8, Vs[b_] + (size_t)c1 * 8); \
  } while (0)

#pragma unroll 1
  for (int seg = 0; seg < 2; ++seg){
    const int qt = seg ? (31 - bx) : bx;
    const int nt = qt + 1;
    const int qrow0 = qt * 64 + wid * 16;
    const int q = qrow0 + fr;          // this lane's q-row

    short8 qf[2];
    {
      const u16* qp = qb + ((size_t)h * 2048 + q) * 64 + fg * 8;
      qf[0] = *(const short8*)(qp);
      qf[1] = *(const short8*)(qp + 32);
    }

    float mrow = -1e30f, lrow = 0.f;
    f32x4 o[4];
    for (int df = 0; df < 4; ++df)
      for (int e = 0; e < 4; ++e) o[df][e] = 0.f;

    STAGE_KV(0);
    if (nt > 1) STAGE_KV(1);
    if (nt > 2) STAGE_KV(2);

#pragma unroll 1
    for (int kt = 0; kt < nt; ++kt){
      const int rem = nt - 1 - kt;
      if (rem >= 2)      WAIT_BAR(8);
      else if (rem == 1) WAIT_BAR(4);
      else               WAIT_BAR(0);
      const u16* Kb = Ks[kt & 3];
      const u16* Vb = Vs[kt & 3];

      // S'^T : s[cf][r] = S'[q][kt*64 + (cf>>1)*32 + fg*8 + (cf&1)*4 + r]
      f32x4 s[4];
      __builtin_amdgcn_s_setprio(1);
#pragma unroll
      for (int cf = 0; cf < 4; ++cf){
        for (int e = 0; e < 4; ++e) s[cf][e] = 0.f;
#pragma unroll
        for (int kc = 0; kc < 2; ++kc){
          short8 kf = *(const short8*)(Kb + ck[kc][cf] * 8);
          s[cf] = __builtin_amdgcn_mfma_f32_16x16x32_bf16(kf, qf[kc], s[cf], 0, 0, 0);
        }
      }
      __builtin_amdgcn_s_setprio(0);

      if (kt * 64 + 63 > qrow0){
#pragma unroll
        for (int cf = 0; cf < 4; ++cf){
          const int kb0 = kt * 64 + (cf >> 1) * 32 + (cf & 1) * 4 + fg * 8;
#pragma unroll
          for (int r = 0; r < 4; ++r)
            if (kb0 + r > q) s[cf][r] = -1e30f;
        }
      }

      // lane-local softmax (base-2 domain, raw v_exp_f32) with defer-max
      float m0 = fmaxf(fmaxf(s[0][0], s[0][1]), fmaxf(s[0][2], s[0][3]));
      float m1 = fmaxf(fmaxf(s[1][0], s[1][1]), fmaxf(s[1][2], s[1][3]));
      float m2 = fmaxf(fmaxf(s[2][0], s[2][1]), fmaxf(s[2][2], s[2][3]));
      float m3 = fmaxf(fmaxf(s[3][0], s[3][1]), fmaxf(s[3][2], s[3][3]));
      float mt = fmaxf(fmaxf(m0, m1), fmaxf(m2, m3));
      mt = fmaxf(mt, __shfl_xor(mt, 16));
      mt = fmaxf(mt, __shfl_xor(mt, 32));
      if (!__all(mt <= mrow + 11.5416f)){
        const float mn = fmaxf(mrow, mt);
        const float al = ex2(mrow - mn);
        lrow *= al;
#pragma unroll
        for (int df = 0; df < 4; ++df)
#pragma unroll
          for (int e = 0; e < 4; ++e) o[df][e] *= al;
        mrow = mn;
      }
      float rs = 0.f;
#pragma unroll
      for (int cf = 0; cf < 4; ++cf){
#pragma unroll
        for (int r = 0; r < 4; ++r){
          s[cf][r] = ex2(s[cf][r] - mrow);
          rs += s[cf][r];
        }
      }
      rs += __shfl_xor(rs, 16);
      rs += __shfl_xor(rs, 32);
      lrow += rs;

      union { u32x4 u; short8 s8; } pb_0, pb_1;
      pb_0.u[0] = cvtpk(s[0][0], s[0][1]); pb_0.u[1] = cvtpk(s[0][2], s[0][3]);
      pb_0.u[2] = cvtpk(s[1][0], s[1][1]); pb_0.u[3] = cvtpk(s[1][2], s[1][3]);
      pb_1.u[0] = cvtpk(s[2][0], s[2][1]); pb_1.u[1] = cvtpk(s[2][2], s[2][3]);
      pb_1.u[2] = cvtpk(s[3][0], s[3][1]); pb_1.u[3] = cvtpk(s[3][2], s[3][3]);

      __builtin_amdgcn_s_setprio(1);
#pragma unroll
      for (int df = 0; df < 4; ++df){
        short8 v0 = *(const short8*)(Vb + ck[0][df] * 8);
        short8 v1 = *(const short8*)(Vb + ck[1][df] * 8);
        o[df] = __builtin_amdgcn_mfma_f32_16x16x32_bf16(v0, pb_0.s8, o[df], 0, 0, 0);
        o[df] = __builtin_amdgcn_mfma_f32_16x16x32_bf16(v1, pb_1.s8, o[df], 0, 0, 0);
      }
      __builtin_amdgcn_s_setprio(0);

      __builtin_amdgcn_s_barrier();
      if (kt + 3 < nt) STAGE_KV(kt + 3);
    }

    const float inv = 1.f / lrow;
#pragma unroll
    for (int df = 0; df < 4; ++df){
      u16x4 pk;
#pragma unroll
      for (int e = 0; e < 4; ++e) pk[e] = f2bf(o[df][e] * inv);
      *(u16x4*)(yb + (size_t)q * 2048 + h * 64 + df * 16 + fg * 4) = pk;
    }
  }
#undef STAGE_KV
}

// ---------------- proj GEMM (128x128, 4 waves, paired tiles, stage interval) -----
__global__ __launch_bounds__(256) void gemm_bt(const u16* __restrict__ A,
                                               const u16* __restrict__ B,
                                               float* __restrict__ C,
                                               int M, int N, int K){
  __shared__ __align__(16) u16 As[4][4096];
  __shared__ __align__(16) u16 Bs[4][4096];
  const int bid = blockIdx.x;
  const int xcd = bid & 7, pos = bid >> 3;          // pos in [0,32)
  const int xm = xcd & 1, xn = xcd >> 1;            // XCD grid 2(m) x 4(n)
  const int mIdx = xm * 8 + (pos & 7);
  const int nIdx = xn * 4 + (pos >> 3);
  const int tid  = threadIdx.x;
  const int lane = tid & 63, wid = tid >> 6;
  const int wr = wid >> 1, wc = wid & 1;
  const int fr = lane & 15, fg = lane >> 4;
  const int mBase = mIdx * 128, nBase = nIdx * 128;

  f32x4 acc[4][4];
  for (int m = 0; m < 4; ++m)
    for (int n = 0; n < 4; ++n)
      for (int e = 0; e < 4; ++e) acc[m][n][e] = 0.f;

  const int c0 = tid, c1 = tid + 256;
  const int p0 = c0 >> 2, q0 = ((c0 & 3) - (p0 >> 1)) & 3;
  const int p1 = c1 >> 2, q1 = ((c1 & 3) - (p1 >> 1)) & 3;
  const u16* Ab = A + (size_t)mBase * K;
  const u16* Bb = B + (size_t)nBase * K;

  int ca[4], cb[4];
#pragma unroll
  for (int m = 0; m < 4; ++m){ const int r = wr * 64 + m * 16 + fr; ca[m] = ACHUNK(r, fg); }
#pragma unroll
  for (int n = 0; n < 4; ++n){ const int r = wc * 64 + n * 16 + fr; cb[n] = ACHUNK(r, fg); }

#define STAGE_BT(kt) do {                                                  \
    const int b_ = (kt) & 3;                                               \
    const int kO_ = (kt) * 32;                                             \
    async16(Ab + (size_t)p0 * K + kO_ + q0 * 8, As[b_] + c0 * 8);          \
    async16(Ab + (size_t)p1 * K + kO_ + q1 * 8, As[b_] + c1 * 8);          \
    async16(Bb + (size_t)p0 * K + kO_ + q0 * 8, Bs[b_] + c0 * 8);          \
    async16(Bb + (size_t)p1 * K + kO_ + q1 * 8, Bs[b_] + c1 * 8);          \
  } while (0)

  STAGE_BT(0); STAGE_BT(1); STAGE_BT(2); STAGE_BT(3);

  const int np = K >> 6;   // pairs
#pragma unroll 1
  for (int p = 0; p < np; ++p){
    if (p < np - 1) WAIT_BAR(8);
    else            WAIT_BAR(0);
#pragma unroll
    for (int kk = 0; kk < 2; ++kk){
      const int cur = (2 * p + kk) & 3;
      short8 a[4], b[4];
#pragma unroll
      for (int m = 0; m < 4; ++m)
        a[m] = *(const short8*)(As[cur] + ca[m] * 8);
#pragma unroll
      for (int n = 0; n < 4; ++n)
        b[n] = *(const short8*)(Bs[cur] + cb[n] * 8);
      __builtin_amdgcn_s_setprio(1);
#pragma unroll
      for (int m = 0; m < 4; ++m)
#pragma unroll
        for (int n = 0; n < 4; ++n)
          acc[m][n] = __builtin_amdgcn_mfma_f32_16x16x32_bf16(a[m], b[n], acc[m][n], 0, 0, 0);
      __builtin_amdgcn_s_setprio(0);
    }
    __builtin_amdgcn_s_barrier();
    if (p < np - 2){ STAGE_BT(2 * p + 4); STAGE_BT(2 * p + 5); }
  }
#undef STAGE_BT

  for (int m = 0; m < 4; ++m){
    const int row = mBase + wr * 64 + m * 16 + fg * 4;
    for (int n = 0; n < 4; ++n){
      const int col = nBase + wc * 64 + n * 16 + fr;
      for (int e = 0; e < 4; ++e)
        C[(size_t)(row + e) * N + col] = acc[m][n][e];
    }
  }
}

extern "C" void kernel_launch(void* const* d_in, const int* in_sizes, int n_in,
                              void* d_out, int out_size, void* d_ws, size_t ws_size,
                              hipStream_t stream){
  (void)in_sizes; (void)n_in; (void)out_size; (void)ws_size;
  const float* x     = (const float*)d_in[0];
  const float* Wqkv  = (const float*)d_in[1];
  const float* Wproj = (const float*)d_in[2];
  const float* qg    = (const float*)d_in[3];
  const float* at    = (const float*)d_in[4];
  float* out = (float*)d_out;

  u16* xb     = (u16*)d_ws;              // 2048*2048
  u16* wqkvb  = xb + 4194304;            // 3072*2048
  u16* wprojb = wqkvb + 6291456;         // 2048*2048
  u16* qbuf   = wprojb + 4194304;        // 32*2048*64
  u16* kbuf   = qbuf + 4194304;          // 8*2048*64
  u16* vTb    = kbuf + 1048576;          // 8*64*2048
  u16* ybuf   = vTb + 1048576;           // 2048*2048

  cvt3<<<14336, 256, 0, stream>>>((const float4*)x, (const float4*)Wqkv,
                                  (const float4*)Wproj, xb, wqkvb, wprojb);
  gemm_qkv<<<384, 256, 0, stream>>>(xb, wqkvb, qg, at, qbuf, kbuf, vTb);
  attn_fwd<<<dim3(16, 32), 256, 0, stream>>>(qbuf, kbuf, vTb, ybuf);
  gemm_bt<<<256, 256, 0, stream>>>(ybuf, wprojb, out, 2048, 2048, 2048);
}